// Round 7
// baseline (65.457 us; speedup 1.0000x reference)
//
#include <hip/hip_runtime.h>
#include <math.h>

#define NB       1025
#define M        1024      // half-length complex FFT size
#define FFTN     2048
#define HOP      512
#define NFRAMES  4000
#define BATCH    4
#define OUT_T    2047488   // (F-1)*hop + N - 2*half
#define R_HOPS   8
#define REG_PB   501       // ceil(4003/8)
#define ACC_N    (R_HOPS * HOP)   // 4096 floats = 16 KB
#define PI_F     3.14159265358979323846f

__device__ __forceinline__ float2 cmul(float2 a, float2 b) {
    return make_float2(a.x*b.x - a.y*b.y, a.x*b.y + a.y*b.x);
}
// float2 bank-pair swizzle — b64 wave64 floor is 4 lanes/bank-pair
__device__ __forceinline__ int SW(int i) { return i ^ ((i >> 4) & 15); }

// base-4 digit reversal of 8-bit index (4 digits)
__device__ __forceinline__ int rev4(int j) {
    return ((j & 3) << 6) | (((j >> 2) & 3) << 4) | (((j >> 4) & 3) << 2) | ((j >> 6) & 3);
}

// window_sumsquare at trimmed position p (boundary path, <=4 terms)
__device__ __forceinline__ float wsq_at(int p) {
    int u  = p + FFTN / 2;
    int fm = u >> 9;
    int n0 = u & 511;
    float wsq = 0.f;
    #pragma unroll
    for (int jj = 0; jj < 4; ++jj) {
        int fr = fm - jj;
        if (fr >= 0 && fr < NFRAMES) {
            int n = n0 + (jj << 9);
            float sw = __sinf((PI_F / (float)FFTN) * (float)n);
            float w  = sw * sw;
            wsq += w * w;
        }
    }
    const float tiny = 1.17549435e-38f;
    return (wsq > tiny) ? wsq : 1.0f;
}

// In-place radix-4 DIT stage: butterfly j reads/writes quad idxD + r*Ns.
template<int ST>
__device__ __forceinline__ void stage_ip(float2* buf, int j,
                                         float2 w1, float2 w2, float2 w3) {
    const int Ns   = 1 << (2 * ST);
    const int jm   = j & (Ns - 1);
    const int idxD = ((j >> (2 * ST)) << (2 * ST + 2)) + jm;
    float2 v0 = buf[SW(idxD)];
    float2 v1 = buf[SW(idxD + Ns)];
    float2 v2 = buf[SW(idxD + 2 * Ns)];
    float2 v3 = buf[SW(idxD + 3 * Ns)];
    v1 = cmul(v1, w1); v2 = cmul(v2, w2); v3 = cmul(v3, w3);
    float2 t0 = make_float2(v0.x + v2.x, v0.y + v2.y);
    float2 t1 = make_float2(v0.x - v2.x, v0.y - v2.y);
    float2 t2 = make_float2(v1.x + v3.x, v1.y + v3.y);
    float2 t3 = make_float2(v1.x - v3.x, v1.y - v3.y);
    buf[SW(idxD         )] = make_float2(t0.x + t2.x, t0.y + t2.y);
    buf[SW(idxD +     Ns)] = make_float2(t1.x - t3.y, t1.y + t3.x);
    buf[SW(idxD + 2 * Ns)] = make_float2(t0.x - t2.x, t0.y - t2.y);
    buf[SW(idxD + 3 * Ns)] = make_float2(t1.x + t3.y, t1.y - t3.x);
}

__device__ __forceinline__ void load_spec(const float* __restrict__ sr,
                                          const float* __restrict__ si,
                                          int b, int f, int j,
                                          float* car, float* cai,
                                          float* cbr, float* cbi) {
    const size_t fb = ((size_t)b * NFRAMES + f) * NB;
    const float* __restrict__ xr = sr + fb;
    const float* __restrict__ xi = si + fb;
    #pragma unroll
    for (int kk = 0; kk < 4; ++kk) {
        int k  = j + kk * 256;
        int mk = M - k;
        car[kk] = xr[k];  cai[kk] = xi[k];
        cbr[kk] = xr[mk]; cbi[kk] = xi[mk];
    }
}

// Hermitian pack + DIT stage 0 (no twiddles), write digit-reversed quad.
__device__ __forceinline__ void pack_st0(float2* buf, int j, int R4,
                                         const float2* tw_pack,
                                         const float* car, const float* cai,
                                         const float* cbr, const float* cbi) {
    float2 z[4];
    #pragma unroll
    for (int kk = 0; kk < 4; ++kk) {
        float arv = car[kk], aiv = cai[kk];
        float brv = cbr[kk], biv = cbi[kk];
        if (kk == 0 && j == 0) { aiv = 0.f; biv = 0.f; }  // DC/Nyquist imag ignored
        float Er = 0.5f * (arv + brv), Ei = 0.5f * (aiv - biv);
        float Dr = 0.5f * (arv - brv), Di = 0.5f * (aiv + biv);
        float2 t = tw_pack[kk];
        float Or = Dr * t.x - Di * t.y;
        float Oi = Dr * t.y + Di * t.x;
        z[kk] = make_float2(Er - Oi, Ei + Or);
    }
    float2 t0 = make_float2(z[0].x + z[2].x, z[0].y + z[2].y);
    float2 t1 = make_float2(z[0].x - z[2].x, z[0].y - z[2].y);
    float2 t2 = make_float2(z[1].x + z[3].x, z[1].y + z[3].y);
    float2 t3 = make_float2(z[1].x - z[3].x, z[1].y - z[3].y);
    buf[SW(4 * R4    )] = make_float2(t0.x + t2.x, t0.y + t2.y);
    buf[SW(4 * R4 + 1)] = make_float2(t1.x - t3.y, t1.y + t3.x);
    buf[SW(4 * R4 + 2)] = make_float2(t0.x - t2.x, t0.y - t2.y);
    buf[SW(4 * R4 + 3)] = make_float2(t1.x + t3.y, t1.y - t3.x);
}

// Stage 4 in registers (natural-order output) + windowed LDS accumulate.
__device__ __forceinline__ void st4_ola(const float2* buf, float2* acc2, int j,
                                        int f_rel, float2 w1, float2 w2, float2 w3,
                                        const float wreg[4][2]) {
    float2 v0 = buf[SW(j)];
    float2 v1 = buf[SW(j + 256)];
    float2 v2 = buf[SW(j + 512)];
    float2 v3 = buf[SW(j + 768)];
    v1 = cmul(v1, w1); v2 = cmul(v2, w2); v3 = cmul(v3, w3);
    float2 t0 = make_float2(v0.x + v2.x, v0.y + v2.y);
    float2 t1 = make_float2(v0.x - v2.x, v0.y - v2.y);
    float2 t2 = make_float2(v1.x + v3.x, v1.y + v3.y);
    float2 t3 = make_float2(v1.x - v3.x, v1.y - v3.y);
    float2 g[4];
    g[0] = make_float2(t0.x + t2.x, t0.y + t2.y);   // n = j
    g[1] = make_float2(t1.x - t3.y, t1.y + t3.x);   // n = j+256
    g[2] = make_float2(t0.x - t2.x, t0.y - t2.y);   // n = j+512
    g[3] = make_float2(t1.x + t3.y, t1.y - t3.x);   // n = j+768
    const int ofs2 = 256 * f_rel;                   // float2 offset (may be <0)
    #pragma unroll
    for (int q = 0; q < 4; ++q) {
        int i2 = ofs2 + j + q * 256;
        if ((unsigned)i2 < (unsigned)(ACC_N / 2)) {
            float2 a = acc2[i2];
            a.x += g[q].x * wreg[q][0];
            a.y += g[q].y * wreg[q][1];
            acc2[i2] = a;
        }
    }
}

// Region-owned OLA; in-place DIT, two frames per barrier segment
// (5 barriers / 2 frames), next-pair spectra prefetched into freed regs.
__global__ __launch_bounds__(256) void istft_region_kernel(
    const float* __restrict__ sr, const float* __restrict__ si,
    float* __restrict__ out)
{
    __shared__ float2 bufA[M];
    __shared__ float2 bufB[M];
    __shared__ float2 acc2[ACC_N / 2];   // 16 KB accumulator

    const int blk = blockIdx.x;
    const int b   = blk / REG_PB;
    const int reg = blk - b * REG_PB;
    const int s0h = reg * R_HOPS;        // first hop owned (untrimmed units)
    const int j   = threadIdx.x;
    const int R4  = rev4(j);

    #pragma unroll
    for (int q = 0; q < ACC_N / 2 / 256; ++q)
        acc2[j + q * 256] = make_float2(0.f, 0.f);

    // ---- per-block precompute (reused across all frames) ----
    float2 tw_pack[4];
    #pragma unroll
    for (int kk = 0; kk < 4; ++kk) {
        int k = j + kk * 256;
        float s, c;
        __sincosf(PI_F * (float)k * (1.0f / (float)M), &s, &c);
        tw_pack[kk] = make_float2(c, s);
    }
    float2 w1s[4], w2s[4], w3s[4];       // DIT stages 1..4
    #pragma unroll
    for (int st = 1; st <= 4; ++st) {
        int Ns = 1 << (2 * st);
        int jm = j & (Ns - 1);
        float ang = (0.5f * PI_F / (float)Ns) * (float)jm;
        float s1, c1;
        __sincosf(ang, &s1, &c1);
        float2 w1 = make_float2(c1, s1);
        w1s[st-1] = w1;
        w2s[st-1] = cmul(w1, w1);
        w3s[st-1] = cmul(w2s[st-1], w1);
    }
    float wreg[4][2];                    // hann(t)^2 / M for t = 2n, 2n+1
    #pragma unroll
    for (int q = 0; q < 4; ++q) {
        int n = j + q * 256;
        #pragma unroll
        for (int h = 0; h < 2; ++h) {
            int t = 2 * n + h;
            float swv = __sinf((PI_F / (float)FFTN) * (float)t);
            wreg[q][h] = swv * swv * (1.0f / 1024.0f);
        }
    }

    int f0 = s0h - 3;           if (f0 < 0)           f0 = 0;
    int f1 = s0h + R_HOPS - 1;  if (f1 > NFRAMES - 1) f1 = NFRAMES - 1;

    __syncthreads();   // acc zeroed

    // ---- preload first pair's spectra ----
    float arA[4], aiA[4], brA[4], biA[4];
    float arB[4], aiB[4], brB[4], biB[4];
    {
        int fB = (f0 + 1 <= f1) ? f0 + 1 : f1;
        load_spec(sr, si, b, f0, j, arA, aiA, brA, biA);
        load_spec(sr, si, b, fB, j, arB, aiB, brB, biB);
    }

    for (int f = f0; f <= f1; f += 2) {
        const bool haveB = (f + 1 <= f1);

        // pack + stage0 (consumes A/B regs)
        pack_st0(bufA, j, R4, tw_pack, arA, aiA, brA, biA);
        if (haveB) pack_st0(bufB, j, R4, tw_pack, arB, aiB, brB, biB);

        // prefetch next pair straight into the freed registers
        {
            int fnA = f + 2;   if (fnA > f1) fnA = f1;
            int fnB = fnA + 1; if (fnB > f1) fnB = f1;
            load_spec(sr, si, b, fnA, j, arA, aiA, brA, biA);
            load_spec(sr, si, b, fnB, j, arB, aiB, brB, biB);
        }

        __syncthreads();
        stage_ip<1>(bufA, j, w1s[0], w2s[0], w3s[0]);
        if (haveB) stage_ip<1>(bufB, j, w1s[0], w2s[0], w3s[0]);
        __syncthreads();
        stage_ip<2>(bufA, j, w1s[1], w2s[1], w3s[1]);
        if (haveB) stage_ip<2>(bufB, j, w1s[1], w2s[1], w3s[1]);
        __syncthreads();
        stage_ip<3>(bufA, j, w1s[2], w2s[2], w3s[2]);
        if (haveB) stage_ip<3>(bufB, j, w1s[2], w2s[2], w3s[2]);
        __syncthreads();

        st4_ola(bufA, acc2, j, f - s0h, w1s[3], w2s[3], w3s[3], wreg);
        if (haveB) st4_ola(bufB, acc2, j, f + 1 - s0h, w1s[3], w2s[3], w3s[3], wreg);

        __syncthreads();   // protect bufA/bufB before next pack
    }

    // ---- epilogue: divide by window_sumsquare, write once, coalesced ----
    const float* accf = (const float*)acc2;
    const int base_u = s0h * HOP;
    float* outb = out + (size_t)b * OUT_T;
    #pragma unroll
    for (int q = 0; q < ACC_N / 256; ++q) {
        int i = j + q * 256;
        int p = base_u + i - FFTN / 2;
        if ((unsigned)p < (unsigned)OUT_T) {
            float invw = (p < 512 || p >= OUT_T - 512) ? (1.0f / wsq_at(p)) : (2.0f / 3.0f);
            outb[p] = accf[i] * invw;
        }
    }
}

extern "C" void kernel_launch(void* const* d_in, const int* in_sizes, int n_in,
                              void* d_out, int out_size, void* d_ws, size_t ws_size,
                              hipStream_t stream) {
    const float* sr = (const float*)d_in[0];
    const float* si = (const float*)d_in[1];
    float* out = (float*)d_out;
    istft_region_kernel<<<BATCH * REG_PB, 256, 0, stream>>>(sr, si, out);
}